// Round 5
// baseline (81.867 us; speedup 1.0000x reference)
//
#include <hip/hip_runtime.h>

#define B 16
#define T 2048
#define D 1024
#define TCHUNK 32
#define MAXBLK (B * (T / TCHUNK))   // 1024 grid upper bound

#define FMA4(c, v, a)                    \
    do {                                 \
        (a).x = fmaf((c), (v).x, (a).x); \
        (a).y = fmaf((c), (v).y, (a).y); \
        (a).z = fmaf((c), (v).z, (a).z); \
        (a).w = fmaf((c), (v).w, (a).w); \
    } while (0)

// ws layout (byte offsets):
//   0     : u32 counters[16]   (zeroed by setup every launch)
//   64    : u32 batchinfo[16]  (start | nc<<16)
//   4096  : u32 map[MAXBLK]    (b | t0<<8 | n<<24), 0xFFFFFFFF = inactive
//   8192  : f32 scores[T]      (normalized softmax)
//   16384 : f32 partials[MAXBLK][D]

// Setup (1 block): softmax scores, dense-prefix worklist map, batch info,
// counter zeroing. Moves ALL per-block preamble work out of the hot kernel.
__global__ __launch_bounds__(256) void setup_kernel(
    const int* __restrict__ lengths, const float* __restrict__ weights,
    unsigned* __restrict__ counters, unsigned* __restrict__ batchinfo,
    unsigned* __restrict__ map, float* __restrict__ scores) {
    const int tid = threadIdx.x;

    // normalized softmax over weights (plain exp: weights~N(0,1), no overflow)
    float e[8];
    float lsum = 0.f;
#pragma unroll
    for (int i = 0; i < 8; ++i) {
        e[i] = expf(weights[tid * 8 + i]);
        lsum += e[i];
    }
#pragma unroll
    for (int off = 32; off > 0; off >>= 1)
        lsum += __shfl_xor(lsum, off);
    __shared__ float red[4];
    if ((tid & 63) == 0) red[tid >> 6] = lsum;
    __syncthreads();
    const float inv = 1.f / (red[0] + red[1] + red[2] + red[3]);
#pragma unroll
    for (int i = 0; i < 8; ++i)
        scores[tid * 8 + i] = e[i] * inv;

    // chunk-count prefix over batches (in registers, all threads redundant)
    int st[B], nc[B], len[B];
    int acc = 0;
#pragma unroll
    for (int i = 0; i < B; ++i) {
        len[i] = lengths[i];
        nc[i]  = max(1, (len[i] + TCHUNK - 1) / TCHUNK);  // len=0 still gets 1
        st[i]  = acc;
        acc += nc[i];
    }
    if (tid < B) {
        counters[tid]  = 0u;
        batchinfo[tid] = (unsigned)st[tid] | ((unsigned)nc[tid] << 16);
    }

    // per-gid map: 4 gids per thread
#pragma unroll
    for (int k = 0; k < 4; ++k) {
        const int gid = tid * 4 + k;
        unsigned m = 0xFFFFFFFFu;
#pragma unroll
        for (int i = 0; i < B; ++i) {
            const int c = gid - st[i];
            if (c >= 0 && c < nc[i]) {
                const int t0 = c * TCHUNK;
                int n = len[i] - t0;
                n = n < 0 ? 0 : (n > TCHUNK ? TCHUNK : n);
                m = (unsigned)i | ((unsigned)t0 << 8) | ((unsigned)n << 24);
            }
        }
        map[gid] = m;
    }
}

// Fused stream + last-block reduce. One u32 preamble load; 32 rows x float4
// stream into registers; 4KB partial store; the block completing its batch
// reduces the contiguous (L2-hot) partials and writes out[b,:] directly.
// ~1024 total atomics on 16 addresses (negligible vs R2's 1M-on-16K).
__global__ __launch_bounds__(256, 4) void fused_kernel(
    const float* __restrict__ input, const unsigned* __restrict__ map,
    const float* __restrict__ scores, float* __restrict__ partials,
    unsigned* __restrict__ counters, const unsigned* __restrict__ batchinfo,
    float* __restrict__ out) {
    const unsigned m = map[blockIdx.x];
    if (m == 0xFFFFFFFFu) return;
    const int b   = m & 0xFFu;
    const int t0  = (m >> 8) & 0xFFFFu;
    const int n   = m >> 24;
    const int tid = threadIdx.x;

    __shared__ float cs[TCHUNK];
    if (tid < TCHUNK)
        cs[tid] = (tid < n) ? scores[t0 + tid] : 0.f;

    const float4* __restrict__ in4 =
        (const float4*)input + ((size_t)b * T + (size_t)t0) * (D / 4) + tid;
    __syncthreads();

    float4 a4 = make_float4(0.f, 0.f, 0.f, 0.f);
    if (n == TCHUNK) {
#pragma unroll 8
        for (int i = 0; i < TCHUNK; ++i) {
            const float4 v = in4[i * (D / 4)];
            FMA4(cs[i], v, a4);
        }
    } else {
        for (int i = 0; i < n; ++i) {
            const float4 v = in4[i * (D / 4)];
            FMA4(cs[i], v, a4);
        }
    }

    ((float4*)partials)[(size_t)blockIdx.x * (D / 4) + tid] = a4;

    // make partial visible device-wide, then bump this batch's counter
    __threadfence();
    __syncthreads();
    __shared__ int s_info, s_last;
    if (tid == 0) {
        const unsigned old = atomicAdd(&counters[b], 1u);
        const unsigned bi  = batchinfo[b];
        s_info = (int)bi;
        s_last = (old == (bi >> 16) - 1u);
    }
    __syncthreads();
    if (!s_last) return;
    __threadfence();   // acquire: all batch partials now visible

    const int start = s_info & 0xFFFF;
    const int nc    = s_info >> 16;
    float4 s4 = make_float4(0.f, 0.f, 0.f, 0.f);
    const float4* __restrict__ p =
        (const float4*)partials + (size_t)start * (D / 4) + tid;
#pragma unroll 4
    for (int c = 0; c < nc; ++c) {
        const float4 v = p[(size_t)c * (D / 4)];
        s4.x += v.x; s4.y += v.y; s4.z += v.z; s4.w += v.w;
    }
    ((float4*)out)[b * (D / 4) + tid] = s4;
}

extern "C" void kernel_launch(void* const* d_in, const int* in_sizes, int n_in,
                              void* d_out, int out_size, void* d_ws, size_t ws_size,
                              hipStream_t stream) {
    const float* input   = (const float*)d_in[0];
    const int*   lengths = (const int*)d_in[1];
    const float* weights = (const float*)d_in[2];
    float* out = (float*)d_out;
    char*  ws  = (char*)d_ws;

    unsigned* counters  = (unsigned*)(ws + 0);
    unsigned* batchinfo = (unsigned*)(ws + 64);
    unsigned* map       = (unsigned*)(ws + 4096);
    float*    scores    = (float*)(ws + 8192);
    float*    partials  = (float*)(ws + 16384);   // 4 MB

    setup_kernel<<<1, 256, 0, stream>>>(lengths, weights, counters, batchinfo,
                                        map, scores);
    fused_kernel<<<MAXBLK, 256, 0, stream>>>(input, map, scores, partials,
                                             counters, batchinfo, out);
}

// Round 6
// 18.238 us; speedup vs baseline: 4.4889x; 4.4889x over previous
//
#include <hip/hip_runtime.h>

#define B 16
#define T 2048
#define D 1024
#define NSLICE 32            // slice-blocks per batch
#define SLICE (D / NSLICE)   // 32 floats = 8 float4 per block

#define FMA4(c, v, a)                    \
    do {                                 \
        (a).x = fmaf((c), (v).x, (a).x); \
        (a).y = fmaf((c), (v).y, (a).y); \
        (a).z = fmaf((c), (v).z, (a).z); \
        (a).w = fmaf((c), (v).w, (a).w); \
    } while (0)

// Single kernel, single writer per output element. Block (b,s) owns
// out[b, s*32 : s*32+32]. 256 threads = 32 row-phases x 8 float4-cols:
// each iteration streams 32 rows' 128B segments. Coefficients are
// UNNORMALIZED exp(w[r]) computed per-thread (VALU is idle in a
// memory-bound kernel; weights are L1-hot); the softmax denominator is
// computed redundantly per block AFTER the stream; LDS tree-reduce over
// row-phases; direct scaled store to out. No scratch, no atomics, no
// fences, no second launch.
__global__ __launch_bounds__(256, 4) void fused1_kernel(
    const float* __restrict__ input,
    const int* __restrict__ lengths,
    const float* __restrict__ weights,
    float* __restrict__ out) {
    const int b   = blockIdx.x >> 5;   // batch
    const int s   = blockIdx.x & 31;   // slice
    const int tid = threadIdx.x;
    const int c   = tid & 7;           // float4 column within slice
    const int rp  = tid >> 3;          // row phase 0..31
    const int len = lengths[b];

    const float4* __restrict__ in4 =
        (const float4*)input + (size_t)b * T * (D / 4) + s * (SLICE / 4) + c;

    float4 acc = make_float4(0.f, 0.f, 0.f, 0.f);

    // full 32-row groups: rows it*32+rp all < len
    const int nfull = len >> 5;
    const float*  wr = weights + rp;
    const float4* p  = in4 + (size_t)rp * (D / 4);
#pragma unroll 4
    for (int it = 0; it < nfull; ++it) {
        const float  cw = expf(wr[it * 32]);
        const float4 v  = p[(size_t)it * 32 * (D / 4)];
        FMA4(cw, v, acc);
    }
    // tail group: mask rows >= len (coeff 0, row not loaded)
    const int r = nfull * 32 + rp;
    if (r < len) {
        const float  cw = expf(weights[r]);
        const float4 v  = in4[(size_t)r * (D / 4)];
        FMA4(cw, v, acc);
    }

    // softmax denominator (redundant per block; ~8 expf/thread, once)
    float lsum = 0.f;
#pragma unroll
    for (int i = 0; i < 8; ++i)
        lsum += expf(weights[tid * 8 + i]);
#pragma unroll
    for (int off = 32; off > 0; off >>= 1)
        lsum += __shfl_xor(lsum, off);
    __shared__ float red[4];
    if ((tid & 63) == 0) red[tid >> 6] = lsum;
    __syncthreads();
    const float inv = 1.f / (red[0] + red[1] + red[2] + red[3]);

    // LDS tree-reduce over the 32 row-phases
    __shared__ float4 lds[32][8];
    lds[rp][c] = acc;
    __syncthreads();
#pragma unroll
    for (int off = 16; off > 0; off >>= 1) {
        if (rp < off) {
            const float4 o = lds[rp + off][c];
            acc.x += o.x; acc.y += o.y; acc.z += o.z; acc.w += o.w;
            lds[rp][c] = acc;
        }
        __syncthreads();
    }

    if (tid < 8) {   // rp==0, c==tid
        const float4 r4 = make_float4(acc.x * inv, acc.y * inv,
                                      acc.z * inv, acc.w * inv);
        ((float4*)out)[b * (D / 4) + s * (SLICE / 4) + tid] = r4;
    }
}

extern "C" void kernel_launch(void* const* d_in, const int* in_sizes, int n_in,
                              void* d_out, int out_size, void* d_ws, size_t ws_size,
                              hipStream_t stream) {
    const float* input   = (const float*)d_in[0];
    const int*   lengths = (const int*)d_in[1];
    const float* weights = (const float*)d_in[2];
    float* out = (float*)d_out;

    fused1_kernel<<<B * NSLICE, 256, 0, stream>>>(input, lengths, weights, out);
}